// Round 15
// baseline (45.755 us; speedup 1.0000x reference)
//
#include <hip/hip_runtime.h>
#include <hip/hip_fp16.h>

typedef _Float16 f16;
typedef __attribute__((ext_vector_type(8))) _Float16 f16x8;
typedef __attribute__((ext_vector_type(4))) _Float16 f16x4;
typedef __attribute__((ext_vector_type(4))) short s16x4;
typedef __attribute__((ext_vector_type(4))) float f32x4;
typedef __attribute__((ext_vector_type(2))) float f32x2;

#define MFMA16(a,b,c) __builtin_amdgcn_mfma_f32_16x16x32_f16(a,b,c,0,0,0)
#define EXP2(x) __builtin_amdgcn_exp2f(x)
#define LOG2E 1.4426950408889634f

#define B_DIM 8
#define L_DIM 2048
#define D_DIM 128
#define NGRP 4
#define KVB 32
#define NTILES 16            // 512 kv per group / 32
#define TILE_B 8192          // 32kv x 128d f16, subtiled [kv4][d16][kv&3][16B-chunks]
#define TILE_H 4096
#define P_ST 40              // P row stride (f16)
#define SLAB_ST 129
#define SLAB_B (8 * 16 * SLAB_ST * 4)   // 66048
#define SMEM_B (SLAB_B + 1024)          // 67072; staging region [0,65536) overlaid by epilogue

__device__ __forceinline__ unsigned ldsa(const void* p) {
    return (unsigned)(unsigned long long)(const __attribute__((address_space(3))) char*)p;
}

#define TRRD(d, a, O) asm volatile("ds_read_b64_tr_b16 %0, %1 offset:" O : "=v"(d) : "v"(a))
#define LGKM0() do { asm volatile("s_waitcnt lgkmcnt(0)" ::: "memory"); __builtin_amdgcn_sched_barrier(0); } while (0)
#define GLDS(gp, lp) __builtin_amdgcn_global_load_lds( \
    (const __attribute__((address_space(1))) unsigned int*)(gp), \
    (__attribute__((address_space(3))) unsigned int*)(lp), 16, 0, 0)

#define PVND(TL, TH, PA, ND) { \
    union { s16x4 s2[2]; f16x8 v; } uu; uu.s2[0] = TL; uu.s2[1] = TH; \
    acc[ND] = MFMA16(PA, uu.v, acc[ND]); }

#define PV_HALF(AREG, PA, S0,S0b,S1,S1b,S2,S2b,S3,S3b, NDB) { \
    s16x4 t0l,t0h,t1l,t1h,t2l,t2h,t3l,t3h; \
    TRRD(t0l, AREG, S0);  TRRD(t0h, AREG, S0b); \
    TRRD(t1l, AREG, S1);  TRRD(t1h, AREG, S1b); \
    TRRD(t2l, AREG, S2);  TRRD(t2h, AREG, S2b); \
    TRRD(t3l, AREG, S3);  TRRD(t3h, AREG, S3b); \
    LGKM0(); \
    __builtin_amdgcn_s_setprio(1); \
    PVND(t0l, t0h, PA, NDB+0); PVND(t1l, t1h, PA, NDB+1); \
    PVND(t2l, t2h, PA, NDB+2); PVND(t3l, t3h, PA, NDB+3); \
    __builtin_amdgcn_s_setprio(0); }

// ---- pre-pass: V f32 -> f16 in chunk-permuted subtile order, one block per 32-kv tile ----
__global__ __launch_bounds__(256) void prep_v(const float* __restrict__ V, f16* __restrict__ ws) {
    const int blk = blockIdx.x;                    // b*64 + tile
    const float* src = V + (size_t)blk * (KVB * D_DIM);
    f16* dst = ws + (size_t)blk * TILE_H;
    const int t = threadIdx.x;
    #pragma unroll
    for (int ii = 0; ii < 2; ++ii) {
        int lin = ii * 256 + t;
        int kv = lin >> 4, oct = lin & 15;         // oct = d/8
        const float* sp = src + kv * D_DIM + oct * 8;
        f32x4 a = *(const f32x4*)sp;
        f32x4 b = *(const f32x4*)(sp + 4);
        // chunk id: (kv>>2)*64 + (d0>>4)*8 + (kv&3)*2 + ((d0>>3)&1)
        int c = (kv >> 2) * 64 + (oct >> 1) * 8 + (kv & 3) * 2 + (oct & 1);
        union { f16 h[8]; f16x8 v; } u;
        #pragma unroll
        for (int k = 0; k < 4; ++k) { u.h[k] = (f16)a[k]; u.h[k + 4] = (f16)b[k]; }
        *(f16x8*)(dst + (size_t)c * 8) = u.v;
    }
}

__global__ __launch_bounds__(512, 4) void attn_fwd(
    const float* __restrict__ Q, const f16* __restrict__ ws, float* __restrict__ Out)
{
    __shared__ __align__(16) char smem[SMEM_B];

    const int tid  = threadIdx.x;
    const int wv   = tid >> 6;
    const int grp  = wv >> 1;      // kv group 0..3 (512 kv each)
    const int qw   = wv & 1;       // q half (16 rows)
    const int lane = tid & 63;
    const int lrow = lane & 15;
    const int g    = lane >> 4;

    const int blk = blockIdx.x;
    const int b   = blk & 7;
    const int q0  = (blk >> 3) * 32;

    char* grpbase = smem + grp * (2 * TILE_B);

    // ---- Q fragments: single-pass fp16, pre-scaled by log2(e); 16 q rows ----
    f16x8 qh[4];
    {
        const float* qp = Q + ((size_t)b * L_DIM + q0 + qw * 16 + lrow) * D_DIM + g * 8;
        #pragma unroll
        for (int dt = 0; dt < 4; ++dt) {
            f32x4 f0 = *(const f32x4*)(qp + dt * 32);
            f32x4 f1 = *(const f32x4*)(qp + dt * 32 + 4);
            #pragma unroll
            for (int i = 0; i < 4; ++i) {
                qh[dt][i]     = (f16)(f0[i] * LOG2E);
                qh[dt][i + 4] = (f16)(f1[i] * LOG2E);
            }
        }
    }

    f32x4 acc[8];
    #pragma unroll
    for (int i = 0; i < 8; ++i) acc[i] = (f32x4)0.0f;
    float m_run = -3.0e38f, l_run = 0.0f;

    // QK A-frag lane offset (bytes within 8KB tile)
    const int qkoff = (lrow >> 2) * 1024 + (g >> 1) * 128 + (lrow & 3) * 32 + (g & 1) * 16;

    const f16* wst = ws + (size_t)b * (64 * TILE_H) + (size_t)(grp * NTILES) * TILE_H;

    // ---- prologue: DMA tile 0 into buf0 (wave qw stages its half) ----
    {
        const f16* w0 = wst + qw * 2048 + lane * 8;
        char* l0 = grpbase + qw * 4096;
        #pragma unroll
        for (int i = 0; i < 4; ++i) GLDS(w0 + i * 512, l0 + i * 1024);
    }
    __syncthreads();

    for (int t = 0; t < NTILES; ++t) {
        const int c = t & 1;
        char* cur = grpbase + c * TILE_B;
        char* alt = grpbase + (c ^ 1) * TILE_B;

        // ---- QK^T swapped: S^T[kv 32][q 16], fp16 1-pass (log2e-scaled) ----
        f32x4 s[2];
        s[0] = (f32x4)0.0f; s[1] = (f32x4)0.0f;
        __builtin_amdgcn_s_setprio(1);
        #pragma unroll
        for (int nt = 0; nt < 2; ++nt) {
            #pragma unroll
            for (int dt = 0; dt < 4; ++dt) {
                f16x8 a = *(const f16x8*)(cur + qkoff + nt * 4096 + dt * 256);
                s[nt] = MFMA16(a, qh[dt], s[nt]);
            }
        }
        __builtin_amdgcn_s_setprio(0);

        // ---- online softmax with defer-max (THR=11.5 in log2 units) ----
        float tm = s[0][0];
        #pragma unroll
        for (int nt = 0; nt < 2; ++nt)
            #pragma unroll
            for (int r = 0; r < 4; ++r) tm = fmaxf(tm, s[nt][r]);
        tm = fmaxf(tm, __shfl_xor(tm, 16));
        tm = fmaxf(tm, __shfl_xor(tm, 32));
        bool need = (tm > m_run + 11.5f);
        if (__any(need)) {
            float mnew = fmaxf(m_run, tm);
            float scl  = EXP2(m_run - mnew);
            m_run = mnew;
            l_run *= scl;
            float sr[4];
            #pragma unroll
            for (int r = 0; r < 4; ++r) sr[r] = __shfl(scl, g * 4 + r);
            #pragma unroll
            for (int nd = 0; nd < 8; ++nd)
                #pragma unroll
                for (int r = 0; r < 4; ++r) acc[nd][r] *= sr[r];
        }
        {
            float ps = 0.0f;
            #pragma unroll
            for (int nt = 0; nt < 2; ++nt)
                #pragma unroll
                for (int r = 0; r < 4; ++r) {
                    float p = EXP2(s[nt][r] - m_run);
                    s[nt][r] = p;
                    ps += p;
                }
            ps += __shfl_xor(ps, 16);
            ps += __shfl_xor(ps, 32);
            l_run += ps;
        }

        // ---- P -> LDS (own qw half of alt, dead data), read back as A-frag ----
        f16* pls = (f16*)(alt + qw * 4096);
        #pragma unroll
        for (int nt = 0; nt < 2; ++nt) {
            f16x4 w = { (f16)s[nt][0], (f16)s[nt][1], (f16)s[nt][2], (f16)s[nt][3] };
            *(f16x4*)(pls + (size_t)lrow * P_ST + nt * 16 + g * 4) = w;
        }
        f16x8 pa = *(const f16x8*)(pls + (size_t)lrow * P_ST + g * 8);
        LGKM0();   // P landed in regs -> safe to DMA-overwrite this half

        // ---- issue DMA staging of tile t+1 into alt (in flight under PV) ----
        if (t + 1 < NTILES) {
            const f16* wnt = wst + (size_t)(t + 1) * TILE_H + qw * 2048 + lane * 8;
            char* ldst = alt + qw * 4096;
            #pragma unroll
            for (int i = 0; i < 4; ++i) GLDS(wnt + i * 512, ldst + i * 1024);
        }

        // ---- PV via hardware transpose reads ----
        // group g reads kv4-blocks 2g (base g*2048) and 2g+1 (+1024); lane own-chunk lrow*8.
        unsigned atr0 = ldsa(cur) + (unsigned)(g * 2048 + lrow * 8);
        PV_HALF(atr0, pa, "0","1024","128","1152","256","1280","384","1408", 0);
        PV_HALF(atr0, pa, "512","1536","640","1664","768","1792","896","1920", 4);

        __syncthreads();   // drains vmcnt (DMA) + lgkm; next iter reads alt
    }

    // ---- cross-group merge (smem repurposed after final barrier) ----
    float* slab = (float*)smem;                 // [8 waves][16 q][SLAB_ST]
    float* mlp  = (float*)(smem + SLAB_B);      // [8 waves][m|l][16]
    #pragma unroll
    for (int nd = 0; nd < 8; ++nd)
        #pragma unroll
        for (int r = 0; r < 4; ++r)
            slab[(size_t)(wv * 16 + g * 4 + r) * SLAB_ST + nd * 16 + lrow] = acc[nd][r];
    if (g == 0) {
        mlp[wv * 32 + lrow]      = m_run;
        mlp[wv * 32 + 16 + lrow] = l_run;
    }
    __syncthreads();

    {
        int row = tid >> 4;                 // 0..31 = qwo*16 + rr
        int dc  = (tid & 15) * 8;
        int qwo = row >> 4, rr = row & 15;
        float mg[4], M = -3.0e38f;
        #pragma unroll
        for (int gg = 0; gg < 4; ++gg) {
            mg[gg] = mlp[(gg * 2 + qwo) * 32 + rr];
            M = fmaxf(M, mg[gg]);
        }
        float L = 0.0f, f[4];
        #pragma unroll
        for (int gg = 0; gg < 4; ++gg) {
            f[gg] = EXP2(mg[gg] - M);
            L += f[gg] * mlp[(gg * 2 + qwo) * 32 + 16 + rr];
        }
        float inv = 1.0f / L;
        float o[8];
        #pragma unroll
        for (int j = 0; j < 8; ++j) o[j] = 0.0f;
        #pragma unroll
        for (int gg = 0; gg < 4; ++gg) {
            const float* sp = &slab[(size_t)((gg * 2 + qwo) * 16 + rr) * SLAB_ST + dc];
            #pragma unroll
            for (int j = 0; j < 8; ++j) o[j] += f[gg] * sp[j];
        }
        f32x4 o0 = { o[0] * inv, o[1] * inv, o[2] * inv, o[3] * inv };
        f32x4 o1 = { o[4] * inv, o[5] * inv, o[6] * inv, o[7] * inv };
        float* op = Out + ((size_t)b * L_DIM + q0 + row) * D_DIM + dc;
        *(f32x4*)op = o0;
        *(f32x4*)(op + 4) = o1;
    }
}

extern "C" void kernel_launch(void* const* d_in, const int* in_sizes, int n_in,
                              void* d_out, int out_size, void* d_ws, size_t ws_size,
                              hipStream_t stream) {
    const float* Q = (const float*)d_in[0];
    const float* V = (const float*)d_in[1];
    float* Out     = (float*)d_out;
    f16* ws        = (f16*)d_ws;   // needs 4 MiB
    prep_v<<<dim3(B_DIM * (L_DIM / KVB)), dim3(256), 0, stream>>>(V, ws);
    attn_fwd<<<dim3(B_DIM * (L_DIM / 32)), dim3(512), 0, stream>>>(Q, ws, Out);
}

// Round 18
// 38.376 us; speedup vs baseline: 1.1923x; 1.1923x over previous
//
#include <hip/hip_runtime.h>
#include <hip/hip_fp16.h>

typedef _Float16 f16;
typedef __attribute__((ext_vector_type(8))) _Float16 f16x8;
typedef __attribute__((ext_vector_type(4))) _Float16 f16x4;
typedef __attribute__((ext_vector_type(4))) short s16x4;
typedef __attribute__((ext_vector_type(4))) float f32x4;
typedef __attribute__((ext_vector_type(2))) float f32x2;
typedef unsigned uint2v __attribute__((ext_vector_type(2)));

#define MFMA16(a,b,c) __builtin_amdgcn_mfma_f32_16x16x32_f16(a,b,c,0,0,0)
#define EXP2(x) __builtin_amdgcn_exp2f(x)
#define LOG2E 1.4426950408889634f

#define B_DIM 8
#define L_DIM 2048
#define D_DIM 128
#define NGRP 4
#define KVB 64
#define NTILES 8             // 512 kv per group / KVB
#define TILE_B 16384         // 64x128 f16, subtiled [kv4][d16][kv&3][16B-chunks]
#define P_ST 72              // P row stride (f16)
#define SLAB_ST 132
#define SMEM_B 137216        // staging 4*2*16384=131072; epilogue slabs 135168+2048

__device__ __forceinline__ unsigned ldsa(const void* p) {
    return (unsigned)(unsigned long long)(const __attribute__((address_space(3))) char*)p;
}

// VALU cross-lane reductions via gfx950 permlane swap builtins (compiler handles
// regalloc + hazards; R16/R17 hand-asm failed: reg coalescing / VALU->permlane hazard).
__device__ __forceinline__ float pl16_max(float x) {
    unsigned u = __float_as_uint(x);
    uint2v r = __builtin_amdgcn_permlane16_swap(u, u, false, false);
    return fmaxf(__uint_as_float(r[0]), __uint_as_float(r[1]));
}
__device__ __forceinline__ float pl32_max(float x) {
    unsigned u = __float_as_uint(x);
    uint2v r = __builtin_amdgcn_permlane32_swap(u, u, false, false);
    return fmaxf(__uint_as_float(r[0]), __uint_as_float(r[1]));
}
__device__ __forceinline__ float pl16_add(float x) {
    unsigned u = __float_as_uint(x);
    uint2v r = __builtin_amdgcn_permlane16_swap(u, u, false, false);
    return __uint_as_float(r[0]) + __uint_as_float(r[1]);
}
__device__ __forceinline__ float pl32_add(float x) {
    unsigned u = __float_as_uint(x);
    uint2v r = __builtin_amdgcn_permlane32_swap(u, u, false, false);
    return __uint_as_float(r[0]) + __uint_as_float(r[1]);
}

#define TRRD(d, a, O) asm volatile("ds_read_b64_tr_b16 %0, %1 offset:" O : "=v"(d) : "v"(a))
#define LGKM0() do { asm volatile("s_waitcnt lgkmcnt(0)" ::: "memory"); __builtin_amdgcn_sched_barrier(0); } while (0)
#define GLDS(gp, lp) __builtin_amdgcn_global_load_lds( \
    (const __attribute__((address_space(1))) unsigned int*)(gp), \
    (__attribute__((address_space(3))) unsigned int*)(lp), 16, 0, 0)

#define PVND(TL, TH, PA0, PA1, ND) { \
    union { s16x4 s2[2]; f16x8 v; } uu; uu.s2[0] = TL; uu.s2[1] = TH; \
    acc[0][ND] = MFMA16(PA0, uu.v, acc[0][ND]); \
    acc[1][ND] = MFMA16(PA1, uu.v, acc[1][ND]); }

#define PV_HALF(AREG, PA0, PA1, S0,S0b,S1,S1b,S2,S2b,S3,S3b, NDB) { \
    s16x4 t0l,t0h,t1l,t1h,t2l,t2h,t3l,t3h; \
    TRRD(t0l, AREG, S0);  TRRD(t0h, AREG, S0b); \
    TRRD(t1l, AREG, S1);  TRRD(t1h, AREG, S1b); \
    TRRD(t2l, AREG, S2);  TRRD(t2h, AREG, S2b); \
    TRRD(t3l, AREG, S3);  TRRD(t3h, AREG, S3b); \
    LGKM0(); \
    __builtin_amdgcn_s_setprio(1); \
    PVND(t0l, t0h, PA0, PA1, NDB+0); PVND(t1l, t1h, PA0, PA1, NDB+1); \
    PVND(t2l, t2h, PA0, PA1, NDB+2); PVND(t3l, t3h, PA0, PA1, NDB+3); \
    __builtin_amdgcn_s_setprio(0); }

// ---- pre-pass: V f32 -> f16 in chunk-permuted subtile order, one block per 64-kv tile ----
__global__ __launch_bounds__(256) void prep_v(const float* __restrict__ V, f16* __restrict__ ws) {
    const int blk = blockIdx.x;                    // b*32 + tt
    const float* src = V + (size_t)blk * (KVB * D_DIM);
    f16* dst = ws + (size_t)blk * (KVB * D_DIM);
    const int t = threadIdx.x;
    #pragma unroll
    for (int ii = 0; ii < 4; ++ii) {
        int lin = ii * 256 + t;
        int kv = lin >> 4, oct = lin & 15;         // oct = d/8
        const float* sp = src + kv * D_DIM + oct * 8;
        f32x4 a = *(const f32x4*)sp;
        f32x4 b = *(const f32x4*)(sp + 4);
        // chunk id for (kv, d0=oct*8): offset/16 = (kv>>2)*64 + (d0>>4)*8 + (kv&3)*2 + ((d0>>3)&1)
        int c = (kv >> 2) * 64 + (oct >> 1) * 8 + (kv & 3) * 2 + (oct & 1);
        union { f16 h[8]; f16x8 v; } u;
        #pragma unroll
        for (int k = 0; k < 4; ++k) { u.h[k] = (f16)a[k]; u.h[k + 4] = (f16)b[k]; }
        *(f16x8*)(dst + (size_t)c * 8) = u.v;
    }
}

__global__ __launch_bounds__(512, 2) void attn_fwd(
    const float* __restrict__ Q, const f16* __restrict__ ws, float* __restrict__ Out)
{
    __shared__ __align__(16) char smem[SMEM_B];

    const int tid  = threadIdx.x;
    const int wv   = tid >> 6;
    const int grp  = wv >> 1;      // kv group 0..3 (512 kv each)
    const int qw   = wv & 1;       // q half (32 rows)
    const int lane = tid & 63;
    const int lrow = lane & 15;
    const int g    = lane >> 4;

    const int blk = blockIdx.x;
    const int b   = blk & 7;
    const int q0  = (blk >> 3) * 64;

    char* grpbase = smem + grp * (2 * TILE_B);

    // ---- Q fragments: single-pass fp16, pre-scaled by log2(e) ----
    f16x8 qh[2][4];
    {
        const float* qb = Q + ((size_t)b * L_DIM + q0 + qw * 32) * D_DIM;
        #pragma unroll
        for (int q2 = 0; q2 < 2; ++q2) {
            const float* qp = qb + (size_t)(q2 * 16 + lrow) * D_DIM + g * 8;
            #pragma unroll
            for (int dt = 0; dt < 4; ++dt) {
                f32x4 f0 = *(const f32x4*)(qp + dt * 32);
                f32x4 f1 = *(const f32x4*)(qp + dt * 32 + 4);
                #pragma unroll
                for (int i = 0; i < 4; ++i) {
                    qh[q2][dt][i]     = (f16)(f0[i] * LOG2E);
                    qh[q2][dt][i + 4] = (f16)(f1[i] * LOG2E);
                }
            }
        }
    }

    f32x4 acc[2][8];
    #pragma unroll
    for (int q2 = 0; q2 < 2; ++q2)
        #pragma unroll
        for (int i = 0; i < 8; ++i) acc[q2][i] = (f32x4)0.0f;
    float m_run[2] = { -3.0e38f, -3.0e38f }, l_run[2] = { 0.0f, 0.0f };

    // QK A-frag lane offset (bytes within tile)
    const int qkoff = (lrow >> 2) * 1024 + (g >> 1) * 128 + (lrow & 3) * 32 + (g & 1) * 16;

    const f16* wsb = ws + (size_t)b * (32 * KVB * D_DIM);   // this batch's ws slice

    // ---- prologue: DMA tile 0 into buf0 ----
    {
        const f16* w0 = wsb + (size_t)(grp * 8) * 8192 + (size_t)(qw * 512 + lane) * 8;
        char* ldst = grpbase + qw * 8192;
        #pragma unroll
        for (int i = 0; i < 8; ++i) GLDS(w0 + i * 512, ldst + i * 1024);
    }
    __syncthreads();

    for (int t = 0; t < NTILES; ++t) {
        const int c = t & 1;
        char* cur = grpbase + c * TILE_B;
        char* alt = grpbase + (c ^ 1) * TILE_B;

        // ---- QK^T swapped: S^T[kv 64][q 32], fp16 1-pass (log2e-scaled) ----
        f32x4 s[2][4];
        #pragma unroll
        for (int q2 = 0; q2 < 2; ++q2)
            #pragma unroll
            for (int nt = 0; nt < 4; ++nt) s[q2][nt] = (f32x4)0.0f;
        __builtin_amdgcn_s_setprio(1);
        #pragma unroll
        for (int nt = 0; nt < 4; ++nt) {
            #pragma unroll
            for (int dt = 0; dt < 4; ++dt) {
                f16x8 a = *(const f16x8*)(cur + qkoff + nt * 4096 + dt * 256);
                s[0][nt] = MFMA16(a, qh[0][dt], s[0][nt]);
                s[1][nt] = MFMA16(a, qh[1][dt], s[1][nt]);
            }
        }
        __builtin_amdgcn_s_setprio(0);

        // ---- online softmax with defer-max (THR=11.5 in log2 units) ----
        float pm[2];
        #pragma unroll
        for (int q2 = 0; q2 < 2; ++q2) {
            float tm = s[q2][0][0];
            #pragma unroll
            for (int nt = 0; nt < 4; ++nt)
                #pragma unroll
                for (int r = 0; r < 4; ++r) tm = fmaxf(tm, s[q2][nt][r]);
            tm = pl16_max(tm);
            tm = pl32_max(tm);
            pm[q2] = tm;
        }
        bool need = (pm[0] > m_run[0] + 11.5f) || (pm[1] > m_run[1] + 11.5f);
        if (__any(need)) {
            float scl[2];
            #pragma unroll
            for (int q2 = 0; q2 < 2; ++q2) {
                float mnew = fmaxf(m_run[q2], pm[q2]);
                scl[q2]  = EXP2(m_run[q2] - mnew);
                m_run[q2] = mnew;
                l_run[q2] *= scl[q2];
            }
            float sr[2][4];
            #pragma unroll
            for (int r = 0; r < 4; ++r) {
                sr[0][r] = __shfl(scl[0], g * 4 + r);
                sr[1][r] = __shfl(scl[1], g * 4 + r);
            }
            #pragma unroll
            for (int q2 = 0; q2 < 2; ++q2)
                #pragma unroll
                for (int nd = 0; nd < 8; ++nd)
                    #pragma unroll
                    for (int r = 0; r < 4; ++r) acc[q2][nd][r] *= sr[q2][r];
        }
        #pragma unroll
        for (int q2 = 0; q2 < 2; ++q2) {
            float ps = 0.0f;
            #pragma unroll
            for (int nt = 0; nt < 4; ++nt)
                #pragma unroll
                for (int r = 0; r < 4; ++r) {
                    float p = EXP2(s[q2][nt][r] - m_run[q2]);
                    s[q2][nt][r] = p;
                    ps += p;
                }
            ps = pl16_add(ps);
            ps = pl32_add(ps);
            l_run[q2] += ps;
        }

        // ---- P -> LDS (dead half of alt buffer), read back as A-frags ----
        f16* pls = (f16*)(alt + qw * 8192);
        #pragma unroll
        for (int q2 = 0; q2 < 2; ++q2) {
            #pragma unroll
            for (int nt = 0; nt < 4; ++nt) {
                f16x4 w = { (f16)s[q2][nt][0], (f16)s[q2][nt][1],
                            (f16)s[q2][nt][2], (f16)s[q2][nt][3] };
                *(f16x4*)(pls + (size_t)(q2 * 16 + lrow) * P_ST + nt * 16 + g * 4) = w;
            }
        }
        f16x8 pa00, pa01, pa10, pa11;
        pa00 = *(const f16x8*)(pls + (size_t)(lrow) * P_ST + g * 8);
        pa01 = *(const f16x8*)(pls + (size_t)(lrow) * P_ST + 32 + g * 8);
        pa10 = *(const f16x8*)(pls + (size_t)(16 + lrow) * P_ST + g * 8);
        pa11 = *(const f16x8*)(pls + (size_t)(16 + lrow) * P_ST + 32 + g * 8);
        LGKM0();   // P reads landed in regs -> safe to DMA-overwrite the slice

        // ---- issue DMA staging of tile t+1 into alt (stays in flight under PV) ----
        if (t + 1 < NTILES) {
            const f16* wnt = wsb + (size_t)(grp * 8 + t + 1) * 8192 + (size_t)(qw * 512 + lane) * 8;
            char* ldst = alt + qw * 8192;
            #pragma unroll
            for (int i = 0; i < 8; ++i) GLDS(wnt + i * 512, ldst + i * 1024);
        }

        // ---- PV via hardware transpose reads ----
        unsigned atr0 = ldsa(cur) + (unsigned)(g * 2048 + lrow * 8);
        unsigned atr1 = atr0 + 8192u;
        PV_HALF(atr0, pa00, pa10, "0","1024","128","1152","256","1280","384","1408", 0);
        PV_HALF(atr0, pa00, pa10, "512","1536","640","1664","768","1792","896","1920", 4);
        PV_HALF(atr1, pa01, pa11, "0","1024","128","1152","256","1280","384","1408", 0);
        PV_HALF(atr1, pa01, pa11, "512","1536","640","1664","768","1792","896","1920", 4);

        __syncthreads();   // drains vmcnt (DMA) + lgkm; next iter reads alt
    }

    // ---- cross-group merge (smem repurposed after final barrier) ----
    float* slab = (float*)smem;                          // [8 waves][32 q][SLAB_ST]
    float* mlp  = (float*)(smem + 8 * 32 * SLAB_ST * 4); // [8 waves][2][32]
    #pragma unroll
    for (int q2 = 0; q2 < 2; ++q2)
        #pragma unroll
        for (int nd = 0; nd < 8; ++nd)
            #pragma unroll
            for (int r = 0; r < 4; ++r)
                slab[(size_t)(wv * 32 + q2 * 16 + g * 4 + r) * SLAB_ST + nd * 16 + lrow] = acc[q2][nd][r];
    if (g == 0) {
        #pragma unroll
        for (int q2 = 0; q2 < 2; ++q2) {
            mlp[wv * 64 + q2 * 16 + lrow]      = m_run[q2];
            mlp[wv * 64 + 32 + q2 * 16 + lrow] = l_run[q2];
        }
    }
    __syncthreads();

    #pragma unroll
    for (int rr = 0; rr < 8; ++rr) {
        int row = wv * 8 + rr;
        int qws = row >> 5, ql = row & 31;
        float mg[4], M = -3.0e38f;
        #pragma unroll
        for (int gg = 0; gg < 4; ++gg) {
            mg[gg] = mlp[(gg * 2 + qws) * 64 + ql];
            M = fmaxf(M, mg[gg]);
        }
        float L = 0.0f, f[4];
        #pragma unroll
        for (int gg = 0; gg < 4; ++gg) {
            f[gg] = EXP2(mg[gg] - M);
            L += f[gg] * mlp[(gg * 2 + qws) * 64 + 32 + ql];
        }
        float inv = 1.0f / L;
        f32x2 o = { 0.0f, 0.0f };
        #pragma unroll
        for (int gg = 0; gg < 4; ++gg) {
            f32x2 v = *(const f32x2*)&slab[(size_t)((gg * 2 + qws) * 32 + ql) * SLAB_ST + lane * 2];
            o[0] += f[gg] * v[0];
            o[1] += f[gg] * v[1];
        }
        o[0] *= inv; o[1] *= inv;
        *(f32x2*)&Out[((size_t)b * L_DIM + q0 + row) * D_DIM + lane * 2] = o;
    }
}

extern "C" void kernel_launch(void* const* d_in, const int* in_sizes, int n_in,
                              void* d_out, int out_size, void* d_ws, size_t ws_size,
                              hipStream_t stream) {
    const float* Q = (const float*)d_in[0];
    const float* V = (const float*)d_in[1];
    float* Out     = (float*)d_out;
    f16* ws        = (f16*)d_ws;   // needs 4 MiB
    prep_v<<<dim3(B_DIM * (L_DIM / KVB)), dim3(256), 0, stream>>>(V, ws);
    attn_fwd<<<dim3(B_DIM * (L_DIM / 64)), dim3(512), 0, stream>>>(Q, ws, Out);
}